// Round 3
// baseline (118.501 us; speedup 1.0000x reference)
//
#include <hip/hip_runtime.h>
#include <math.h>

#define NROW 384
#define NCOL 512

// ---------------------------------------------------------------------------
// ws layout (float offsets):
//   hp[4] : 4 x 196608 @ 0        layer-1 K-split partials [branch*2+slice]
//   gp[4] : 4 x 196608 @ 786432   layer-2 K-split partials
//   m1p   : 6*512      @ 1572864  y column-sum partials
//   m2p   : 6*512      @ 1575936  y column-sumsq partials
//   part  : 192 dbl    @ 1579008  (byte 6316032, 8B aligned)
//   cnt   : 1 int      @ 1579392
// total ~6.3 MB (all L2/L3 resident)
// ---------------------------------------------------------------------------
#define HP_OFF   0
#define GP_OFF   786432
#define M1_OFF   1572864
#define M2_OFF   1575936
#define PART_OFF 1579008
#define CNT_OFF  1579392

// GEMM block: C[32x64 tile] (+)= A[32 x 256 k-slice] @ W[256 x 64 slice].
// 128 threads, 2 waves, 4x4 micro-tile, TK=32, 8 K-iterations.
// COMBINE: A element = relu(A0 + A1 + bias1[k]) (layer-2 consuming split
// layer-1 partials); else A element = A0 (layer-1 reading x).
template<bool COMBINE>
__device__ __forceinline__ void gemm32x64(
    const float* __restrict__ A0, const float* __restrict__ A1,
    const float* __restrict__ bias1,
    const float* __restrict__ W, float* __restrict__ C,
    int m0, int n0, int ca)
{
    // pad 34: As store = 2-way bank conflict (free, m136); b64-aligned reads
    __shared__ __align__(16) float As[32][34];
    __shared__ __align__(16) float Bs[32][64];

    const int t  = threadIdx.x;
    const int tx = t & 15;          // 4 cols each
    const int ty = t >> 4;          // 0..7, 4 rows each
    const int r_a = t >> 3;         // A stage: rows r_a, r_a+16
    const int kg  = (t & 7) * 4;    // A stage: k-group (4 floats)
    const int kr  = t >> 4;         // B stage: rows kr + 8*i
    const int cg  = (t & 15) * 4;   // B stage: col group

    float4 a_pf0, a_pf1, c_pf0, c_pf1, bb_pf;
    float4 b_pf[4];

    auto load_iter = [&](int k0) {
        const float* a0p = &A0[(size_t)(m0 + r_a) * NCOL + ca + k0 + kg];
        a_pf0 = *(const float4*)a0p;
        a_pf1 = *(const float4*)(a0p + 16 * NCOL);
        if (COMBINE) {
            const float* a1p = &A1[(size_t)(m0 + r_a) * NCOL + ca + k0 + kg];
            c_pf0 = *(const float4*)a1p;
            c_pf1 = *(const float4*)(a1p + 16 * NCOL);
            bb_pf = *(const float4*)&bias1[ca + k0 + kg];
        }
        #pragma unroll
        for (int i = 0; i < 4; ++i)
            b_pf[i] = *(const float4*)&W[(size_t)(ca + k0 + kr + 8 * i) * NCOL + n0 + cg];
    };

    float acc[4][4] = {};
    load_iter(0);

    for (int it = 0; it < 8; ++it) {
        __syncthreads();
        {
            float av0[4], av1[4];
            *(float4*)av0 = a_pf0; *(float4*)av1 = a_pf1;
            if (COMBINE) {
                float cv0[4], cv1[4], bv[4];
                *(float4*)cv0 = c_pf0; *(float4*)cv1 = c_pf1;
                *(float4*)bv  = bb_pf;
                #pragma unroll
                for (int j = 0; j < 4; ++j) {
                    av0[j] = fmaxf(av0[j] + cv0[j] + bv[j], 0.f);
                    av1[j] = fmaxf(av1[j] + cv1[j] + bv[j], 0.f);
                }
            }
            #pragma unroll
            for (int j = 0; j < 4; ++j) {
                As[kg + j][r_a]      = av0[j];
                As[kg + j][r_a + 16] = av1[j];
            }
            #pragma unroll
            for (int i = 0; i < 4; ++i)
                *(float4*)&Bs[kr + 8 * i][cg] = b_pf[i];
        }
        __syncthreads();
        if (it < 7) load_iter((it + 1) * 32);

        #pragma unroll
        for (int kk = 0; kk < 32; ++kk) {
            float av[4], bv[4];
            *(float2*)&av[0] = *(const float2*)&As[kk][ty * 4];
            *(float2*)&av[2] = *(const float2*)&As[kk][ty * 4 + 2];
            *(float4*)bv     = *(const float4*)&Bs[kk][tx * 4];
            #pragma unroll
            for (int i = 0; i < 4; ++i) {
                acc[i][0] += av[i] * bv[0];
                acc[i][1] += av[i] * bv[1];
                acc[i][2] += av[i] * bv[2];
                acc[i][3] += av[i] * bv[3];
            }
        }
    }

    #pragma unroll
    for (int i = 0; i < 4; ++i) {
        float4 o = make_float4(acc[i][0], acc[i][1], acc[i][2], acc[i][3]);
        *(float4*)&C[(size_t)(m0 + ty * 4 + i) * NCOL + n0 + tx * 4] = o;
    }
}

// Kernel 1: layer-1 K-split GEMM partials, 384 blocks (branch x slice x 12 x 8)
// + 6 y-stat blocks. Also zeroes the k3 completion counter.
__global__ __launch_bounds__(128, 2) void k_layer1(
    const float* __restrict__ x,
    const float* __restrict__ w1mu, const float* __restrict__ w1lv,
    const float* __restrict__ y, float* __restrict__ ws)
{
    const int b = blockIdx.x;
    const int t = threadIdx.x;

    if (b == 0 && t == 0) *(int*)(ws + CNT_OFF) = 0;

    if (b >= 384) {
        // y column moments: 64 rows per block, each thread owns 4 columns.
        const int sb = b - 384;
        const int c  = t * 4;
        float s1[4] = {0.f, 0.f, 0.f, 0.f};
        float s2[4] = {0.f, 0.f, 0.f, 0.f};
        #pragma unroll 4
        for (int r = 0; r < 64; ++r) {
            float v[4];
            *(float4*)v = *(const float4*)&y[(size_t)(sb * 64 + r) * NCOL + c];
            #pragma unroll
            for (int j = 0; j < 4; ++j) { s1[j] += v[j]; s2[j] += v[j] * v[j]; }
        }
        *(float4*)&ws[M1_OFF + sb * NCOL + c] = make_float4(s1[0], s1[1], s1[2], s1[3]);
        *(float4*)&ws[M2_OFF + sb * NCOL + c] = make_float4(s2[0], s2[1], s2[2], s2[3]);
        return;
    }

    const int branch = b / 192;
    const int rem    = b % 192;
    const int sl     = rem / 96;
    const int mt     = (rem % 96) >> 3;
    const int nt     = rem & 7;

    const float* W = branch ? w1lv : w1mu;
    float* C = ws + HP_OFF + (size_t)(branch * 2 + sl) * 196608;
    gemm32x64<false>(x, nullptr, nullptr, W, C, mt * 32, nt * 64, sl * 256);
}

// Kernel 2: layer-2 K-split GEMM partials; A-loader fuses relu(h0+h1+b1).
__global__ __launch_bounds__(128, 2) void k_layer2(
    const float* __restrict__ w2mu, const float* __restrict__ b1mu,
    const float* __restrict__ w2lv, const float* __restrict__ b1lv,
    float* __restrict__ ws)
{
    const int b = blockIdx.x;
    const int branch = b / 192;
    const int rem    = b % 192;
    const int sl     = rem / 96;
    const int mt     = (rem % 96) >> 3;
    const int nt     = rem & 7;

    const float* A0 = ws + HP_OFF + (size_t)(branch * 2 + 0) * 196608;
    const float* A1 = ws + HP_OFF + (size_t)(branch * 2 + 1) * 196608;
    const float* bias1 = branch ? b1lv : b1mu;
    const float* W = branch ? w2lv : w2mu;
    float* C = ws + GP_OFF + (size_t)(branch * 2 + sl) * 196608;
    gemm32x64<true>(A0, A1, bias1, W, C, mt * 32, nt * 64, sl * 256);
}

// Kernel 3: elementwise epilogue + block reduction + last-block final reduce.
// 192 blocks x 256 threads, 1 float4 per thread.
__global__ __launch_bounds__(256) void k_epilogue(
    const float* __restrict__ b2mu, const float* __restrict__ b2lv,
    const float* __restrict__ y, float* __restrict__ ws,
    float* __restrict__ out)
{
    __shared__ double wsum[4];
    __shared__ int is_last;

    const int t = threadIdx.x;
    const float inv_b = 1.0f / (float)NROW;

    const int e4   = blockIdx.x * 256 + t;
    const int col4 = e4 & 127;
    const size_t off = (size_t)e4 * 4;

    const float* gm0 = ws + GP_OFF;
    const float* gm1 = ws + GP_OFF + 196608;
    const float* gl0 = ws + GP_OFF + 2 * 196608;
    const float* gl1 = ws + GP_OFF + 3 * 196608;

    float gm[4], gq[4], gl[4], gr[4], yv[4], bm[4], bl[4], s1[4], s2[4];
    *(float4*)gm = *(const float4*)&gm0[off];
    *(float4*)gq = *(const float4*)&gm1[off];
    *(float4*)gl = *(const float4*)&gl0[off];
    *(float4*)gr = *(const float4*)&gl1[off];
    *(float4*)yv = *(const float4*)&y[off];
    *(float4*)bm = *(const float4*)&b2mu[col4 * 4];
    *(float4*)bl = *(const float4*)&b2lv[col4 * 4];
    #pragma unroll
    for (int j = 0; j < 4; ++j) { s1[j] = 0.f; s2[j] = 0.f; }
    #pragma unroll
    for (int p = 0; p < 6; ++p) {
        float p1[4], p2[4];
        *(float4*)p1 = *(const float4*)&ws[M1_OFF + p * NCOL + col4 * 4];
        *(float4*)p2 = *(const float4*)&ws[M2_OFF + p * NCOL + col4 * 4];
        #pragma unroll
        for (int j = 0; j < 4; ++j) { s1[j] += p1[j]; s2[j] += p2[j]; }
    }

    float tsum = 0.f;
    #pragma unroll
    for (int j = 0; j < 4; ++j) {
        const float m1 = s1[j] * inv_b;
        const float m2 = s2[j] * inv_b;
        const float mu = gm[j] + gq[j] + bm[j];
        const float lv = tanhf(gl[j] + gr[j] + bl[j]);
        const float iv = expf(-lv);
        tsum += iv * ((yv[j] * yv[j] - m2) + 2.f * mu * (m1 - yv[j]));
    }

    float s = tsum;
    #pragma unroll
    for (int o = 32; o > 0; o >>= 1) s += __shfl_down(s, o);
    if ((t & 63) == 0) wsum[t >> 6] = (double)s;
    __syncthreads();

    double* partials = (double*)(ws + PART_OFF);
    int* counter = (int*)(ws + CNT_OFF);
    if (t == 0) {
        partials[blockIdx.x] = wsum[0] + wsum[1] + wsum[2] + wsum[3];
        __threadfence();
        const int old = atomicAdd(counter, 1);
        is_last = (old == 191) ? 1 : 0;
    }
    __syncthreads();

    if (is_last && t < 64) {
        __threadfence();
        double v = partials[t] + partials[t + 64] + partials[t + 128];
        #pragma unroll
        for (int o = 32; o > 0; o >>= 1) v += __shfl_down(v, o);
        if (t == 0) {
            // C0 = log1p(exp(-20)/383) — the broadcast-bug logsumexp constant
            const double C0 = 5.381602146862063e-12;
            out[0] = (float)(-0.5 * v / (double)NROW - C0);
        }
    }
}

extern "C" void kernel_launch(void* const* d_in, const int* in_sizes, int n_in,
                              void* d_out, int out_size, void* d_ws, size_t ws_size,
                              hipStream_t stream) {
    const float* x    = (const float*)d_in[0];
    const float* y    = (const float*)d_in[1];
    const float* w1mu = (const float*)d_in[2];
    const float* b1mu = (const float*)d_in[3];
    const float* w2mu = (const float*)d_in[4];
    const float* b2mu = (const float*)d_in[5];
    const float* w1lv = (const float*)d_in[6];
    const float* b1lv = (const float*)d_in[7];
    const float* w2lv = (const float*)d_in[8];
    const float* b2lv = (const float*)d_in[9];
    float* out = (float*)d_out;
    float* ws  = (float*)d_ws;

    k_layer1<<<390, 128, 0, stream>>>(x, w1mu, w1lv, y, ws);
    k_layer2<<<384, 128, 0, stream>>>(w2mu, b1mu, w2lv, b1lv, ws);
    k_epilogue<<<192, 256, 0, stream>>>(b2mu, b2lv, y, ws, out);
}

// Round 4
// 112.157 us; speedup vs baseline: 1.0566x; 1.0566x over previous
//
#include <hip/hip_runtime.h>
#include <math.h>

#define NROW 384
#define NCOL 512

// ---------------------------------------------------------------------------
// ws layout (float offsets):
//   hp  : 8 x 196608 @ 0        layer-1 partials [branch*4 + slice]
//   gp  : 8 x 196608 @ 1572864  layer-2 partials [branch*4 + slice]
//   m1p : 12*512     @ 3145728  y column-sum partials
//   m2p : 12*512     @ 3151872  y column-sumsq partials
//   m1  : 512        @ 3158016  reduced column sums
//   m2  : 512        @ 3158528
//   part: 192 dbl    @ 3159040  (byte 12636160, 8B aligned)
//   cnt : 1 int      @ 3159424
// total ~12.6 MB (L2/L3 resident)
// ---------------------------------------------------------------------------
#define HP_OFF   0
#define GP_OFF   1572864
#define M1P_OFF  3145728
#define M2P_OFF  3151872
#define M1_OFF   3158016
#define M2_OFF   3158528
#define PART_OFF 3159040
#define CNT_OFF  3159424
#define SLICE    196608

// GEMM block: C[32x64] = A[32 x 128 k-slice] @ W[128 x 64 slice].
// 128 threads (2 waves), 4x4 micro-tile, TK=32, 4 K-iters, double-buffered
// LDS, one barrier per iter. All LDS reads are ds_read_b128 (pads 36/68 keep
// 16B row alignment: 144 B / 272 B).
// NS=1: A read directly. NS=4: A element = relu(sum of 4 slices + bias1[k]).
template<int NS>
__device__ __forceinline__ void gemm_block(
    const float* __restrict__ A, const float* __restrict__ bias1,
    const float* __restrict__ W, float* __restrict__ C,
    int m0, int n0, int ca)
{
    __shared__ __align__(16) float As[2][32][36];
    __shared__ __align__(16) float Bs[2][32][68];

    const int t  = threadIdx.x;
    const int tx = t & 15;          // B cols: n0 + tx*4
    const int ty = t >> 4;          // A rows: m0 + ty*4 + i
    // staging: A tile 32m x 32k = 256 f4 -> 2/thread; B tile 32k x 64n = 512 f4 -> 4/thread
    const int am0 = t >> 3;         // A rows am0, am0+16
    const int ak4 = (t & 7) * 4;    // A k-group
    const int bk  = t >> 4;         // B rows bk + 8q
    const int bn4 = (t & 15) * 4;   // B col group

    float4 a_raw[2][NS];
    float4 b_raw[4];
    float4 bias_raw;

    auto load_it = [&](int k0) {
        #pragma unroll
        for (int p = 0; p < 2; ++p) {
            const size_t aoff = (size_t)(m0 + am0 + p * 16) * NCOL + ca + k0 + ak4;
            #pragma unroll
            for (int s = 0; s < NS; ++s)
                a_raw[p][s] = *(const float4*)&A[(size_t)s * SLICE + aoff];
        }
        if (NS > 1) bias_raw = *(const float4*)&bias1[ca + k0 + ak4];
        #pragma unroll
        for (int q = 0; q < 4; ++q)
            b_raw[q] = *(const float4*)&W[(size_t)(ca + k0 + bk + 8 * q) * NCOL + n0 + bn4];
    };

    auto store_it = [&](int buf) {
        #pragma unroll
        for (int p = 0; p < 2; ++p) {
            float v[4];
            if (NS == 1) {
                *(float4*)v = a_raw[p][0];
            } else {
                float s0[4], s1[4], s2[4], s3[4], bb[4];
                *(float4*)s0 = a_raw[p][0]; *(float4*)s1 = a_raw[p][1];
                *(float4*)s2 = a_raw[p][2]; *(float4*)s3 = a_raw[p][3];
                *(float4*)bb = bias_raw;
                #pragma unroll
                for (int j = 0; j < 4; ++j)
                    v[j] = fmaxf(s0[j] + s1[j] + s2[j] + s3[j] + bb[j], 0.f);
            }
            #pragma unroll
            for (int j = 0; j < 4; ++j)
                As[buf][ak4 + j][am0 + p * 16] = v[j];   // k-major transpose
        }
        #pragma unroll
        for (int q = 0; q < 4; ++q)
            *(float4*)&Bs[buf][bk + 8 * q][bn4] = b_raw[q];
    };

    float acc[4][4] = {};

    load_it(0);
    store_it(0);
    __syncthreads();
    load_it(32);

    for (int it = 0; it < 4; ++it) {
        if (it < 3) {
            store_it((it + 1) & 1);           // fill alt buffer (waits vmcnt)
            if (it < 2) load_it((it + 2) * 32);
        }
        const int buf = it & 1;
        #pragma unroll
        for (int kk = 0; kk < 32; ++kk) {
            float av[4], bv[4];
            *(float4*)av = *(const float4*)&As[buf][kk][ty * 4];   // ds_read_b128
            *(float4*)bv = *(const float4*)&Bs[buf][kk][tx * 4];   // ds_read_b128
            #pragma unroll
            for (int i = 0; i < 4; ++i) {
                acc[i][0] += av[i] * bv[0];
                acc[i][1] += av[i] * bv[1];
                acc[i][2] += av[i] * bv[2];
                acc[i][3] += av[i] * bv[3];
            }
        }
        __syncthreads();
    }

    #pragma unroll
    for (int i = 0; i < 4; ++i)
        *(float4*)&C[(size_t)(m0 + ty * 4 + i) * NCOL + n0 + tx * 4] =
            make_float4(acc[i][0], acc[i][1], acc[i][2], acc[i][3]);
}

// Kernel 1: layer-1 GEMM partials (768 blocks: br x 4 slices x 12 x 8 tiles)
// + 12 y column-moment blocks.
__global__ __launch_bounds__(128, 2) void k_layer1(
    const float* __restrict__ x,
    const float* __restrict__ w1mu, const float* __restrict__ w1lv,
    const float* __restrict__ y, float* __restrict__ ws)
{
    const int b = blockIdx.x;
    const int t = threadIdx.x;

    if (b >= 768) {
        // y column moments: 32 rows per block, thread owns 4 columns
        const int sb = b - 768;
        const int c  = t * 4;
        float s1[4] = {0.f, 0.f, 0.f, 0.f};
        float s2[4] = {0.f, 0.f, 0.f, 0.f};
        #pragma unroll 4
        for (int r = 0; r < 32; ++r) {
            float v[4];
            *(float4*)v = *(const float4*)&y[(size_t)(sb * 32 + r) * NCOL + c];
            #pragma unroll
            for (int j = 0; j < 4; ++j) { s1[j] += v[j]; s2[j] += v[j] * v[j]; }
        }
        *(float4*)&ws[M1P_OFF + sb * NCOL + c] = make_float4(s1[0], s1[1], s1[2], s1[3]);
        *(float4*)&ws[M2P_OFF + sb * NCOL + c] = make_float4(s2[0], s2[1], s2[2], s2[3]);
        return;
    }

    const int sl   = b & 3;
    const int br   = (b >> 2) & 1;
    const int tile = b >> 3;             // 0..95
    const int mt   = tile >> 3;          // 12 M-tiles of 32
    const int nt   = tile & 7;           // 8 N-tiles of 64

    gemm_block<1>(x, nullptr, br ? w1lv : w1mu,
                  ws + HP_OFF + (size_t)(br * 4 + sl) * SLICE,
                  mt * 32, nt * 64, sl * 128);
}

// Kernel 2: layer-2 GEMM partials; A-loader fuses relu(sum4 + b1).
// Block 768 reduces the y-stat partials and zeroes the k3 counter.
__global__ __launch_bounds__(128, 2) void k_layer2(
    const float* __restrict__ b1mu, const float* __restrict__ b1lv,
    const float* __restrict__ w2mu, const float* __restrict__ w2lv,
    float* __restrict__ ws)
{
    const int b = blockIdx.x;
    const int t = threadIdx.x;

    if (b == 768) {
        if (t == 0) *(int*)(ws + CNT_OFF) = 0;
        const int c = t * 4;
        float s1[4] = {0.f, 0.f, 0.f, 0.f};
        float s2[4] = {0.f, 0.f, 0.f, 0.f};
        #pragma unroll
        for (int p = 0; p < 12; ++p) {
            float p1[4], p2[4];
            *(float4*)p1 = *(const float4*)&ws[M1P_OFF + p * NCOL + c];
            *(float4*)p2 = *(const float4*)&ws[M2P_OFF + p * NCOL + c];
            #pragma unroll
            for (int j = 0; j < 4; ++j) { s1[j] += p1[j]; s2[j] += p2[j]; }
        }
        *(float4*)&ws[M1_OFF + c] = make_float4(s1[0], s1[1], s1[2], s1[3]);
        *(float4*)&ws[M2_OFF + c] = make_float4(s2[0], s2[1], s2[2], s2[3]);
        return;
    }

    const int sl   = b & 3;
    const int br   = (b >> 2) & 1;
    const int tile = b >> 3;
    const int mt   = tile >> 3;
    const int nt   = tile & 7;

    gemm_block<4>(ws + HP_OFF + (size_t)(br * 4) * SLICE,
                  br ? b1lv : b1mu, br ? w2lv : w2mu,
                  ws + GP_OFF + (size_t)(br * 4 + sl) * SLICE,
                  mt * 32, nt * 64, sl * 128);
}

// Kernel 3: elementwise epilogue + block reduction + last-block final reduce.
// 192 blocks x 256 threads, 1 float4 per thread.
__global__ __launch_bounds__(256) void k_epilogue(
    const float* __restrict__ b2mu, const float* __restrict__ b2lv,
    const float* __restrict__ y, float* __restrict__ ws,
    float* __restrict__ out)
{
    __shared__ double wsum[4];
    __shared__ int is_last;

    const int t = threadIdx.x;
    const float inv_b = 1.0f / (float)NROW;

    const int e4   = blockIdx.x * 256 + t;
    const int col4 = e4 & 127;
    const size_t off = (size_t)e4 * 4;

    const float* gpm = ws + GP_OFF;                 // mu slices 0..3
    const float* gpl = ws + GP_OFF + 4 * SLICE;     // lv slices 0..3

    float gm[4] = {0.f, 0.f, 0.f, 0.f};
    float gl[4] = {0.f, 0.f, 0.f, 0.f};
    #pragma unroll
    for (int s = 0; s < 4; ++s) {
        float a[4], c[4];
        *(float4*)a = *(const float4*)&gpm[(size_t)s * SLICE + off];
        *(float4*)c = *(const float4*)&gpl[(size_t)s * SLICE + off];
        #pragma unroll
        for (int j = 0; j < 4; ++j) { gm[j] += a[j]; gl[j] += c[j]; }
    }

    float yv[4], bm[4], bl[4], m1v[4], m2v[4];
    *(float4*)yv  = *(const float4*)&y[off];
    *(float4*)bm  = *(const float4*)&b2mu[col4 * 4];
    *(float4*)bl  = *(const float4*)&b2lv[col4 * 4];
    *(float4*)m1v = *(const float4*)&ws[M1_OFF + col4 * 4];
    *(float4*)m2v = *(const float4*)&ws[M2_OFF + col4 * 4];

    float tsum = 0.f;
    #pragma unroll
    for (int j = 0; j < 4; ++j) {
        const float m1 = m1v[j] * inv_b;
        const float m2 = m2v[j] * inv_b;
        const float mu = gm[j] + bm[j];
        const float lv = tanhf(gl[j] + bl[j]);
        const float iv = expf(-lv);
        tsum += iv * ((yv[j] * yv[j] - m2) + 2.f * mu * (m1 - yv[j]));
    }

    float s = tsum;
    #pragma unroll
    for (int o = 32; o > 0; o >>= 1) s += __shfl_down(s, o);
    if ((t & 63) == 0) wsum[t >> 6] = (double)s;
    __syncthreads();

    double* partials = (double*)(ws + PART_OFF);
    int* counter = (int*)(ws + CNT_OFF);
    if (t == 0) {
        partials[blockIdx.x] = wsum[0] + wsum[1] + wsum[2] + wsum[3];
        __threadfence();
        const int old = atomicAdd(counter, 1);
        is_last = (old == 191) ? 1 : 0;
    }
    __syncthreads();

    if (is_last && t < 64) {
        __threadfence();
        double v = partials[t] + partials[t + 64] + partials[t + 128];
        #pragma unroll
        for (int o = 32; o > 0; o >>= 1) v += __shfl_down(v, o);
        if (t == 0) {
            // C0 = log1p(exp(-20)/383) — the broadcast-bug logsumexp constant
            const double C0 = 5.381602146862063e-12;
            out[0] = (float)(-0.5 * v / (double)NROW - C0);
        }
    }
}

extern "C" void kernel_launch(void* const* d_in, const int* in_sizes, int n_in,
                              void* d_out, int out_size, void* d_ws, size_t ws_size,
                              hipStream_t stream) {
    const float* x    = (const float*)d_in[0];
    const float* y    = (const float*)d_in[1];
    const float* w1mu = (const float*)d_in[2];
    const float* b1mu = (const float*)d_in[3];
    const float* w2mu = (const float*)d_in[4];
    const float* b2mu = (const float*)d_in[5];
    const float* w1lv = (const float*)d_in[6];
    const float* b1lv = (const float*)d_in[7];
    const float* w2lv = (const float*)d_in[8];
    const float* b2lv = (const float*)d_in[9];
    float* out = (float*)d_out;
    float* ws  = (float*)d_ws;

    k_layer1<<<780, 128, 0, stream>>>(x, w1mu, w1lv, y, ws);
    k_layer2<<<769, 128, 0, stream>>>(b1mu, b1lv, w2mu, w2lv, ws);
    k_epilogue<<<192, 256, 0, stream>>>(b2mu, b2lv, y, ws, out);
}